// Round 11
// baseline (415.122 us; speedup 1.0000x reference)
//
#include <hip/hip_runtime.h>
#include <float.h>
#include <math.h>

#define D 1024
#define BQ 256
#define NMEM 100000
#define TOPK 16
#define NT_TOT 1563   // 64-col tiles covering 100032 >= 100000
#define SIMS_BLOCKS 1024

typedef __attribute__((ext_vector_type(4))) float f32x4;
typedef __attribute__((ext_vector_type(8))) short s16x8;

__device__ __forceinline__ void mfma16(f32x4& d, s16x8 a, s16x8 b) {
  asm("v_mfma_f32_16x16x32_bf16 %0, %1, %2, %0" : "+v"(d) : "v"(a), "v"(b));
}

__device__ __forceinline__ unsigned short bf16rtne(float x) {
  unsigned u = __float_as_uint(x);
  unsigned r = u + 0x7fffu + ((u >> 16) & 1u);
  return (unsigned short)(r >> 16);
}

__device__ __forceinline__ void cvt8(float4 a, float4 b, s16x8* hi, s16x8* lo,
                                     float* ssq) {
  float xs[8] = {a.x, a.y, a.z, a.w, b.x, b.y, b.z, b.w};
  union { s16x8 v; unsigned short u[8]; } H, L;
#pragma unroll
  for (int e = 0; e < 8; ++e) {
    float x = xs[e];
    unsigned short h = bf16rtne(x);
    float hf = __uint_as_float(((unsigned)h) << 16);
    H.u[e] = (short)h;
    L.u[e] = (short)bf16rtne(x - hf);
    *ssq = fmaf(x, x, *ssq);
  }
  *hi = H.v;
  *lo = L.v;
}

// ---------------- reductions ----------------

__device__ __forceinline__ float waveReduceSum(float v) {
#pragma unroll
  for (int o = 32; o > 0; o >>= 1) v += __shfl_xor(v, o, 64);
  return v;
}

__device__ __forceinline__ float blockReduceSum(float v, float* sbuf) {
  v = waveReduceSum(v);
  int w = threadIdx.x >> 6;
  if ((threadIdx.x & 63) == 0) sbuf[w] = v;
  __syncthreads();
  float r = sbuf[0] + sbuf[1] + sbuf[2] + sbuf[3];
  __syncthreads();
  return r;
}

// ---------------- prep: split [R][1024] f32 into bf16 hi/lo frag layout ----

__global__ __launch_bounds__(256) void prep_bf16_kernel(
    const float* __restrict__ src, float* __restrict__ dst, int R16) {
  int g = blockIdx.x * 256 + threadIdx.x;
  int l = g & 63;
  int mt = (g >> 6) % R16;
  int kb = (g >> 6) / R16;
  int row = mt * 16 + (l & 15);
  int k0 = kb * 32 + ((l >> 4) << 3);
  const float* s = src + (size_t)row * D + k0;
  float4 v0 = *(const float4*)s;
  float4 v1 = *(const float4*)(s + 4);
  float xs[8] = {v0.x, v0.y, v0.z, v0.w, v1.x, v1.y, v1.z, v1.w};
  union { uint4 q; unsigned short u[8]; } H, L;
#pragma unroll
  for (int e = 0; e < 8; ++e) {
    float x = xs[e];
    unsigned short h = bf16rtne(x);
    float hf = __uint_as_float(((unsigned)h) << 16);
    H.u[e] = h;
    L.u[e] = bf16rtne(x - hf);
  }
  char* db = (char*)dst + (size_t)kb * (R16 * 2048) + mt * 2048 + l * 16;
  *(uint4*)db = H.q;
  *(uint4*)(db + 1024) = L.q;
}

// ---------------- MFMA projection GEMM (K-chunked, bf16 single-acc) --------

__global__ __launch_bounds__(256) void mfma_gemm_kernel(
    const float* __restrict__ Afr, const float* __restrict__ Wfr,
    float* __restrict__ part) {
  int t = threadIdx.x;
  int w = t >> 6, l = t & 63;
  int ct = blockIdx.x & 63;
  int kc = blockIdx.x >> 6;
  f32x4 acc[4];
  f32x4 zz = {0.f, 0.f, 0.f, 0.f};
#pragma unroll
  for (int mi = 0; mi < 4; ++mi) acc[mi] = zz;
  const char* ab0 = (const char*)Afr + w * 8192 + l * 16;
  const char* bb0 = (const char*)Wfr + ct * 2048 + l * 16;
#pragma unroll 2
  for (int s = 0; s < 8; ++s) {
    int kb = kc * 8 + s;
    const char* bb = bb0 + (size_t)kb * 131072;
    s16x8 bh = *(const s16x8*)(bb);
    s16x8 bl = *(const s16x8*)(bb + 1024);
    const char* ab = ab0 + (size_t)kb * 32768;
#pragma unroll
    for (int mi = 0; mi < 4; ++mi) {
      s16x8 ah = *(const s16x8*)(ab + mi * 2048);
      s16x8 al = *(const s16x8*)(ab + mi * 2048 + 1024);
      mfma16(acc[mi], ah, bh);
      mfma16(acc[mi], ah, bl);
      mfma16(acc[mi], al, bh);
    }
  }
  float* pb = part + (size_t)kc * 262144 + ct * 16 + (l & 15);
#pragma unroll
  for (int mi = 0; mi < 4; ++mi)
#pragma unroll
    for (int j = 0; j < 4; ++j) {
      int row = w * 64 + mi * 16 + ((l >> 4) << 2) + j;
      pb[(size_t)row * 1024] = acc[mi][j];
    }
}

// ------- reduce partials + bias + LayerNorm + GELU -> Hf bf16 frags --------

__global__ __launch_bounds__(256) void reduce_ln_gelu_kernel(
    const float* __restrict__ part, const float* __restrict__ bias,
    const float* __restrict__ g, const float* __restrict__ b,
    float* __restrict__ Hf) {
  __shared__ float sbuf[4];
  int row = blockIdx.x, t = threadIdx.x;
  const float* p = part + (size_t)row * 1024 + t * 4;
  float4 x0 = *(const float4*)(p);
  float4 x1 = *(const float4*)(p + 262144);
  float4 x2 = *(const float4*)(p + 524288);
  float4 x3 = *(const float4*)(p + 786432);
  float4 bb = *(const float4*)(bias + t * 4);
  float vx = x0.x + x1.x + x2.x + x3.x + bb.x;
  float vy = x0.y + x1.y + x2.y + x3.y + bb.y;
  float vz = x0.z + x1.z + x2.z + x3.z + bb.z;
  float vw = x0.w + x1.w + x2.w + x3.w + bb.w;
  float s = blockReduceSum(vx + vy + vz + vw, sbuf);
  float mu = s * (1.0f / D);
  float dx = vx - mu, dy = vy - mu, dz = vz - mu, dw = vw - mu;
  float ss = blockReduceSum(dx * dx + dy * dy + dz * dz + dw * dw, sbuf);
  float rstd = rsqrtf(ss * (1.0f / D) + 1e-5f);
  float4 gg = *(const float4*)(g + t * 4);
  float4 be = *(const float4*)(b + t * 4);
  float y[4];
  y[0] = dx * rstd * gg.x + be.x;
  y[1] = dy * rstd * gg.y + be.y;
  y[2] = dz * rstd * gg.z + be.z;
  y[3] = dw * rstd * gg.w + be.w;
  const float c = 0.70710678118654752f;
  union { uint2 q; unsigned short u[4]; } H, L;
#pragma unroll
  for (int e = 0; e < 4; ++e) {
    float ye = 0.5f * y[e] * (1.0f + erff(y[e] * c));
    unsigned short h = bf16rtne(ye);
    float hf = __uint_as_float(((unsigned)h) << 16);
    H.u[e] = h;
    L.u[e] = bf16rtne(ye - hf);
  }
  int kb = t >> 3, oct = (t >> 1) & 3;
  char* db = (char*)Hf + (size_t)kb * 32768 + (row >> 4) * 2048 +
             ((row & 15) + oct * 16) * 16 + (t & 1) * 8;
  *(uint2*)db = H.q;
  *(uint2*)(db + 1024) = L.q;
}

// ------- reduce partials + bias + L2 norm -> out_refined + Af bf16 frags ---

__global__ __launch_bounds__(256) void reduce_l2norm_kernel(
    const float* __restrict__ part, const float* __restrict__ bias,
    float* __restrict__ outRef, float* __restrict__ Af) {
  __shared__ float sbuf[4];
  int row = blockIdx.x, t = threadIdx.x;
  const float* p = part + (size_t)row * 1024 + t * 4;
  float4 x0 = *(const float4*)(p);
  float4 x1 = *(const float4*)(p + 262144);
  float4 x2 = *(const float4*)(p + 524288);
  float4 x3 = *(const float4*)(p + 786432);
  float4 bb = *(const float4*)(bias + t * 4);
  float vx = x0.x + x1.x + x2.x + x3.x + bb.x;
  float vy = x0.y + x1.y + x2.y + x3.y + bb.y;
  float vz = x0.z + x1.z + x2.z + x3.z + bb.z;
  float vw = x0.w + x1.w + x2.w + x3.w + bb.w;
  float ss = blockReduceSum(vx * vx + vy * vy + vz * vz + vw * vw, sbuf);
  float inv = 1.0f / fmaxf(sqrtf(ss), 1e-12f);
  float y[4] = {vx * inv, vy * inv, vz * inv, vw * inv};
  *(float4*)(outRef + (size_t)row * D + t * 4) =
      make_float4(y[0], y[1], y[2], y[3]);
  union { uint2 q; unsigned short u[4]; } H, L;
#pragma unroll
  for (int e = 0; e < 4; ++e) {
    unsigned short h = bf16rtne(y[e]);
    float hf = __uint_as_float(((unsigned)h) << 16);
    H.u[e] = h;
    L.u[e] = bf16rtne(y[e] - hf);
  }
  int kb = t >> 3, oct = (t >> 1) & 3;
  char* db = (char*)Af + (size_t)kb * 32768 + (row >> 4) * 2048 +
             ((row & 15) + oct * 16) * 16 + (t & 1) * 8;
  *(uint2*)db = H.q;
  *(uint2*)(db + 1024) = L.q;
}

__global__ void zero_ctrs_kernel(int* c) { c[threadIdx.x] = 0; }

// ---------------- sims GEMM: 256x64 tiles, B-only LDS, reg-prefetched A ----
// BYTE-IDENTICAL to the R9 kernel that passed (414us). Only the grid grew
// 512->1024 (work-stealing makes grid size semantically inert): with
// VGPR=128 and 16.9KB LDS the HW co-schedules 4 blocks/CU. Launch bounds
// stay (256,2) — R10 showed forcing min-waves=4 (exact-VGPR cap) corrupts.

#define SBODY(J, BP, ACh, ACl, ANh, ANl, RC0, RC1, RP0, RP1, DOPFB, DOPFA,    \
              DOCONV)                                                          \
  do {                                                                         \
    if (DOCONV) {                                                              \
      s16x8 bhn_, bln_;                                                        \
      cvt8(RC0, RC1, &bhn_, &bln_, &ssq);                                      \
      char* bw_ = smem + (1 - (BP)) * 8192 + bwoff;                            \
      *(s16x8*)bw_ = bhn_;                                                     \
      *(s16x8*)(bw_ + 1024) = bln_;                                            \
    }                                                                          \
    if (DOPFA) {                                                               \
      const char* an_ = afbytes + (size_t)((J) + 1) * 32768 + w4x + l * 16;    \
      _Pragma("unroll") for (int mi = 0; mi < 4; ++mi) {                       \
        ANh[mi] = *(const s16x8*)(an_ + mi * 2048);                            \
        ANl[mi] = *(const s16x8*)(an_ + mi * 2048 + 1024);                     \
      }                                                                        \
    }                                                                          \
    if (DOPFB) {                                                               \
      const float* p_ = bsrc + ((J) + 3) * 32;                                 \
      RP0 = *(const float4*)p_;                                                \
      RP1 = *(const float4*)(p_ + 4);                                          \
    }                                                                          \
    __builtin_amdgcn_s_setprio(1);                                             \
    _Pragma("unroll") for (int ni = 0; ni < 4; ++ni) {                         \
      const char* bb_ = smem + (BP)*8192 + ni * 2048 + l * 16;                 \
      s16x8 bh_ = *(const s16x8*)bb_;                                          \
      s16x8 bl_ = *(const s16x8*)(bb_ + 1024);                                 \
      _Pragma("unroll") for (int mi = 0; mi < 4; ++mi) {                       \
        mfma16(acc[mi][ni], ACh[mi], bh_);                                     \
        mfma16(acc[mi][ni], ACh[mi], bl_);                                     \
        mfma16(acc[mi][ni], ACl[mi], bh_);                                     \
      }                                                                        \
    }                                                                          \
    __builtin_amdgcn_s_setprio(0);                                             \
    asm volatile("s_waitcnt lgkmcnt(0)\n\ts_barrier" ::: "memory");            \
    __builtin_amdgcn_sched_barrier(0);                                         \
  } while (0)

__global__ __launch_bounds__(256, 2) void sims_gemm_kernel(
    const float* __restrict__ Afrag, const float* __restrict__ mem,
    float* __restrict__ invn, int* __restrict__ ctr,
    float* __restrict__ simsbuf, int ntiles, int chunk_n0, int stride_cols) {
  __shared__ __align__(16) char smem[16384];  // bufB[2] only
  __shared__ float sInvF[64];
  __shared__ int s_tile;
  const int t = threadIdx.x;
  const int w = t >> 6, l = t & 63;
  const int w4x = (w * 4) * 2048;
  // B roles (R5-proven): row t>>2 of tile, k-octet t&3
  const int brow_loc = t >> 2;
  const int kseg = t & 3;
  const int bwoff = (brow_loc >> 4) * 2048 + ((brow_loc & 15) + kseg * 16) * 16;
  const char* afbytes = (const char*)Afrag;

  while (true) {
    if (t == 0) s_tile = atomicAdd(ctr, 1);
    __syncthreads();
    const int unit = s_tile;
    __syncthreads();
    if (unit >= ntiles) break;
    const int n0 = chunk_n0 + unit * 64;
    const int brow = min(n0 + brow_loc, NMEM - 1);
    const float* bsrc = mem + (size_t)brow * D + kseg * 8;

    f32x4 acc[4][4];
    f32x4 zz = {0.f, 0.f, 0.f, 0.f};
#pragma unroll
    for (int mi = 0; mi < 4; ++mi)
#pragma unroll
      for (int ni = 0; ni < 4; ++ni) acc[mi][ni] = zz;
    float ssq = 0.f;

    // register sets: braw R0..R2 (each 2 float4), A-frags S0,S1 (each 8 s16x8)
    float4 r0a, r0b, r1a, r1b, r2a, r2b;
    s16x8 s0h[4], s0l[4], s1h[4], s1l[4];

    // ---- prologue: braw0..2 + A(0) loads (plain), conv(0)->bufB0, barrier
    r0a = *(const float4*)bsrc;
    r0b = *(const float4*)(bsrc + 4);
    r1a = *(const float4*)(bsrc + 32);
    r1b = *(const float4*)(bsrc + 36);
    r2a = *(const float4*)(bsrc + 64);
    r2b = *(const float4*)(bsrc + 68);
    {
      const char* a0_ = afbytes + w4x + l * 16;
#pragma unroll
      for (int mi = 0; mi < 4; ++mi) {
        s0h[mi] = *(const s16x8*)(a0_ + mi * 2048);
        s0l[mi] = *(const s16x8*)(a0_ + mi * 2048 + 1024);
      }
    }
    {
      s16x8 bh0, bl0;
      cvt8(r0a, r0b, &bh0, &bl0, &ssq);
      *(s16x8*)(smem + bwoff) = bh0;
      *(s16x8*)(smem + bwoff + 1024) = bl0;
    }
    asm volatile("s_waitcnt lgkmcnt(0)\n\ts_barrier" ::: "memory");
    __builtin_amdgcn_sched_barrier(0);

    // ---- steps 0..23 (mod-6 schedule)
#pragma unroll 1
    for (int jb = 0; jb < 24; jb += 6) {
      SBODY(jb + 0, 0, s0h, s0l, s1h, s1l, r1a, r1b, r0a, r0b, 1, 1, 1);
      SBODY(jb + 1, 1, s1h, s1l, s0h, s0l, r2a, r2b, r1a, r1b, 1, 1, 1);
      SBODY(jb + 2, 0, s0h, s0l, s1h, s1l, r0a, r0b, r2a, r2b, 1, 1, 1);
      SBODY(jb + 3, 1, s1h, s1l, s0h, s0l, r1a, r1b, r0a, r0b, 1, 1, 1);
      SBODY(jb + 4, 0, s0h, s0l, s1h, s1l, r2a, r2b, r1a, r1b, 1, 1, 1);
      SBODY(jb + 5, 1, s1h, s1l, s0h, s0l, r0a, r0b, r2a, r2b, 1, 1, 1);
    }
    // ---- steps 24..29 (last braw prefetch at J=28 -> braw31)
    SBODY(24, 0, s0h, s0l, s1h, s1l, r1a, r1b, r0a, r0b, 1, 1, 1);
    SBODY(25, 1, s1h, s1l, s0h, s0l, r2a, r2b, r1a, r1b, 1, 1, 1);
    SBODY(26, 0, s0h, s0l, s1h, s1l, r0a, r0b, r2a, r2b, 1, 1, 1);
    SBODY(27, 1, s1h, s1l, s0h, s0l, r1a, r1b, r0a, r0b, 1, 1, 1);
    SBODY(28, 0, s0h, s0l, s1h, s1l, r2a, r2b, r1a, r1b, 1, 1, 1);
    SBODY(29, 1, s1h, s1l, s0h, s0l, r0a, r0b, r2a, r2b, 0, 1, 1);
    // ---- step 30: conv braw31 (r1), prefetch A31; step 31: compute only
    SBODY(30, 0, s0h, s0l, s1h, s1l, r1a, r1b, r0a, r0b, 0, 1, 1);
    SBODY(31, 1, s1h, s1l, s0h, s0l, r2a, r2b, r1a, r1b, 0, 0, 0);

    // ---- epilogue: col norms via shfl (octet lanes t^1,t^2), scaled store
    float s2 = ssq + __shfl_xor(ssq, 1, 64);
    s2 = s2 + __shfl_xor(s2, 2, 64);
    float inv = 1.0f / fmaxf(sqrtf(s2), 1e-12f);
    if (kseg == 0) {
      sInvF[brow_loc] = inv;
      int col = n0 + brow_loc;
      if (col < NMEM) invn[col] = inv;
    }
    __syncthreads();
    float siv[4];
#pragma unroll
    for (int ni = 0; ni < 4; ++ni) siv[ni] = sInvF[ni * 16 + (l & 15)];
    float* srow = simsbuf + (size_t)(unit * 64);
#pragma unroll
    for (int mi = 0; mi < 4; ++mi)
#pragma unroll
      for (int jj = 0; jj < 4; ++jj) {
        int row = w * 64 + mi * 16 + ((l >> 4) << 2) + jj;
        float* rp = srow + (size_t)row * stride_cols;
#pragma unroll
        for (int ni = 0; ni < 4; ++ni)
          rp[ni * 16 + (l & 15)] = acc[mi][ni][jj] * siv[ni];
      }
    __syncthreads();  // sInvF reads done before next tile overwrites
  }
}

// -------- per-(row, column-segment) top-16 scan over scaled sims -----------
// blockIdx.x = row + 256*seg. Each block scans cols [seg*seglen, ...) of its
// row; per-segment top-16 lists are merged globally by final_merge (top-16
// of a union is partition-invariant under the (val desc, idx asc) order).

__global__ __launch_bounds__(512) void topk_chunk_kernel(
    const float* __restrict__ simsbuf, int stride_cols, int chunk_n0,
    int nvalid, int seglen, float* __restrict__ cv, int* __restrict__ ci) {
  __shared__ float wvv[8];
  __shared__ int wii[8];
  __shared__ float sbv;
  __shared__ int sbi;
  int row = blockIdx.x & 255;
  int seg = blockIdx.x >> 8;
  int c0beg = seg * seglen;
  int c0end = c0beg + seglen;
  if (c0end > nvalid) c0end = nvalid;
  int t = threadIdx.x;
  const float* S = simsbuf + (size_t)row * stride_cols;
  float tv[16];
  int ti[16];
#pragma unroll
  for (int s = 0; s < 16; ++s) { tv[s] = -FLT_MAX; ti[s] = 2147483647; }
  float curMin = -FLT_MAX;
  for (int c0 = c0beg + t * 4; c0 < c0end; c0 += 2048) {
    float vv[4] = {-FLT_MAX, -FLT_MAX, -FLT_MAX, -FLT_MAX};
    if (c0 + 4 <= c0end) {
      float4 v = *(const float4*)(S + c0);
      vv[0] = v.x; vv[1] = v.y; vv[2] = v.z; vv[3] = v.w;
    } else {
#pragma unroll
      for (int e = 0; e < 4; ++e)
        if (c0 + e < c0end) vv[e] = S[c0 + e];
    }
#pragma unroll
    for (int e = 0; e < 4; ++e) {
      float v = vv[e];
      if (v > curMin) {
        int n = chunk_n0 + c0 + e;
        int ms = 0;
        float mv = tv[0];
#pragma unroll
        for (int s = 1; s < 16; ++s)
          if (tv[s] < mv) { mv = tv[s]; ms = s; }
#pragma unroll
        for (int s = 0; s < 16; ++s)
          if (s == ms) { tv[s] = v; ti[s] = n; }
        curMin = tv[0];
#pragma unroll
        for (int s = 1; s < 16; ++s) curMin = fminf(curMin, tv[s]);
      }
    }
  }
  float lastV = FLT_MAX;
  int lastI = -1;
  for (int pass = 0; pass < TOPK; ++pass) {
    float bv = -FLT_MAX;
    int bi = 2147483647;
#pragma unroll
    for (int s = 0; s < 16; ++s) {
      float v = tv[s];
      int idx = ti[s];
      bool qual = (v < lastV) || (v == lastV && idx > lastI);
      bool bet = (v > bv) || (v == bv && idx < bi);
      if (qual && bet) { bv = v; bi = idx; }
    }
#pragma unroll
    for (int o = 32; o > 0; o >>= 1) {
      float v2 = __shfl_xor(bv, o, 64);
      int i2 = __shfl_xor(bi, o, 64);
      if (v2 > bv || (v2 == bv && i2 < bi)) { bv = v2; bi = i2; }
    }
    if ((t & 63) == 0) { wvv[t >> 6] = bv; wii[t >> 6] = bi; }
    __syncthreads();
    if (t == 0) {
      float fv = wvv[0];
      int fi = wii[0];
#pragma unroll
      for (int u = 1; u < 8; ++u) {
        if (wvv[u] > fv || (wvv[u] == fv && wii[u] < fi)) {
          fv = wvv[u];
          fi = wii[u];
        }
      }
      sbv = fv;
      sbi = fi;
      cv[seg * 4096 + row * TOPK + pass] = fv;
      ci[seg * 4096 + row * TOPK + pass] = fi;
    }
    __syncthreads();
    lastV = sbv;
    lastI = sbi;
  }
}

// ---------------- final merge across candidate lists -----------------------

__global__ __launch_bounds__(64) void final_merge_kernel(
    const float* __restrict__ cand_v, const int* __restrict__ cand_i,
    int nlists, float* __restrict__ out_vals, float* __restrict__ out_idx) {
  int row = blockIdx.x, l = threadIdx.x;
  int nc = nlists * TOPK;
  float mv[8];
  int mi_[8];
#pragma unroll
  for (int u = 0; u < 8; ++u) {
    int p = l + u * 64;
    if (p < nc) {
      int ch = p >> 4;
      mv[u] = cand_v[ch * 4096 + row * TOPK + (p & 15)];
      mi_[u] = cand_i[ch * 4096 + row * TOPK + (p & 15)];
    } else {
      mv[u] = -FLT_MAX;
      mi_[u] = 2147483647;
    }
  }
  float lastV = FLT_MAX;
  int lastI = -1;
  for (int pass = 0; pass < TOPK; ++pass) {
    float bv = -FLT_MAX;
    int bi = 2147483647;
#pragma unroll
    for (int u = 0; u < 8; ++u) {
      bool qual = (mv[u] < lastV) || (mv[u] == lastV && mi_[u] > lastI);
      bool bet = (mv[u] > bv) || (mv[u] == bv && mi_[u] < bi);
      if (qual && bet) { bv = mv[u]; bi = mi_[u]; }
    }
#pragma unroll
    for (int o = 32; o > 0; o >>= 1) {
      float v2 = __shfl_xor(bv, o, 64);
      int i2 = __shfl_xor(bi, o, 64);
      if (v2 > bv || (v2 == bv && i2 < bi)) { bv = v2; bi = i2; }
    }
    bv = __shfl(bv, 0, 64);
    bi = __shfl(bi, 0, 64);
    if (l == 0) {
      out_vals[row * TOPK + pass] = bv;
      out_idx[row * TOPK + pass] = (float)bi;
    }
    lastV = bv;
    lastI = bi;
  }
}

// ---------------- gather retrieved = mem_n[topk_idx] -----------------------

__global__ __launch_bounds__(256) void gather_kernel(
    const float* __restrict__ out_idx, const float* __restrict__ mem,
    const float* __restrict__ invn, float* __restrict__ out_retr) {
  int p = blockIdx.x;
  int idx = (int)out_idx[p];
  float inv = invn[idx];
  int c = threadIdx.x * 4;
  float4 v = *(const float4*)(mem + (size_t)idx * D + c);
  v.x *= inv; v.y *= inv; v.z *= inv; v.w *= inv;
  *(float4*)(out_retr + (size_t)p * D + c) = v;
}

// ---------------- launch ---------------------------------------------------

extern "C" void kernel_launch(void* const* d_in, const int* in_sizes, int n_in,
                              void* d_out, int out_size, void* d_ws,
                              size_t ws_size, hipStream_t stream) {
  const float* query = (const float*)d_in[0];
  const float* W1 = (const float*)d_in[1];
  const float* b1 = (const float*)d_in[2];
  const float* ln_g = (const float*)d_in[3];
  const float* ln_b = (const float*)d_in[4];
  const float* W2 = (const float*)d_in[5];
  const float* b2 = (const float*)d_in[6];
  const float* mem = (const float*)d_in[7];

  float* out = (float*)d_out;
  float* out_refined = out;                    // 262144
  float* out_vals = out + 262144;              // 4096
  float* out_idx = out + 262144 + 4096;        // 4096
  float* out_retr = out + 262144 + 8192;       // 256*16*1024

  float* wsp = (float*)d_ws;
  float* invn = wsp;                           // 100352
  float* Qf = wsp + 100352;                    // 262144 (query frags, then Hf)
  float* Af = wsp + 362496;                    // 262144
  float* W1f = wsp + 624640;                   // 1048576
  float* W2f = wsp + 1673216;                  // 1048576
  float* part = wsp + 2721792;                 // 1048576
  float* cand_v = wsp + 3770368;               // 131072 (32 lists max)
  int* cand_i = (int*)(wsp + 3901440);         // 131072
  int* ctrs = (int*)(wsp + 4032512);           // 64
  float* sims = wsp + 4032576;

  long ws_floats = (long)(ws_size / 4);
  long avail = ws_floats - 4032640;
  int tpc = (int)(avail / 16384);
  if (tpc > NT_TOT) tpc = NT_TOT;
  if (tpc < 1) tpc = 1;
  int nchunk = (NT_TOT + tpc - 1) / tpc;
  if (nchunk > 32) nchunk = 32;
  tpc = (NT_TOT + nchunk - 1) / nchunk;
  int stride = tpc * 64;
  int nseg = (nchunk <= 8) ? 4 : 1;            // nchunk*nseg <= 32

  zero_ctrs_kernel<<<1, 64, 0, stream>>>(ctrs);
  prep_bf16_kernel<<<128, 256, 0, stream>>>(query, Qf, 16);
  prep_bf16_kernel<<<512, 256, 0, stream>>>(W1, W1f, 64);
  prep_bf16_kernel<<<512, 256, 0, stream>>>(W2, W2f, 64);
  mfma_gemm_kernel<<<256, 256, 0, stream>>>(Qf, W1f, part);
  reduce_ln_gelu_kernel<<<256, 256, 0, stream>>>(part, b1, ln_g, ln_b, Qf);
  mfma_gemm_kernel<<<256, 256, 0, stream>>>(Qf, W2f, part);
  reduce_l2norm_kernel<<<256, 256, 0, stream>>>(part, b2, out_refined, Af);
  for (int c = 0; c < nchunk; ++c) {
    int t0 = c * tpc;
    int nt = NT_TOT - t0;
    if (nt > tpc) nt = tpc;
    if (nt <= 0) break;
    int base = t0 * 64;
    sims_gemm_kernel<<<SIMS_BLOCKS, 256, 0, stream>>>(Af, mem, invn, ctrs + c,
                                                      sims, nt, base, stride);
    int nvalid = NMEM - base;
    if (nvalid > nt * 64) nvalid = nt * 64;
    int seglen = ((nvalid + nseg - 1) / nseg + 3) & ~3;
    topk_chunk_kernel<<<256 * nseg, 512, 0, stream>>>(
        sims, stride, base, nvalid, seglen, cand_v + c * nseg * 4096,
        cand_i + c * nseg * 4096);
  }
  final_merge_kernel<<<256, 64, 0, stream>>>(cand_v, cand_i, nchunk * nseg,
                                             out_vals, out_idx);
  gather_kernel<<<BQ * TOPK, 256, 0, stream>>>(out_idx, mem, invn, out_retr);
}

// Round 12
// 372.379 us; speedup vs baseline: 1.1148x; 1.1148x over previous
//
#include <hip/hip_runtime.h>
#include <float.h>
#include <math.h>

#define D 1024
#define BQ 256
#define NMEM 100000
#define TOPK 16
#define NT_TOT 1563   // 64-col tiles covering 100032 >= 100000
#define SIMS_BLOCKS 512

typedef __attribute__((ext_vector_type(4))) float f32x4;
typedef __attribute__((ext_vector_type(8))) short s16x8;

__device__ __forceinline__ void mfma16(f32x4& d, s16x8 a, s16x8 b) {
  asm("v_mfma_f32_16x16x32_bf16 %0, %1, %2, %0" : "+v"(d) : "v"(a), "v"(b));
}

__device__ __forceinline__ unsigned short bf16rtne(float x) {
  unsigned u = __float_as_uint(x);
  unsigned r = u + 0x7fffu + ((u >> 16) & 1u);
  return (unsigned short)(r >> 16);
}

__device__ __forceinline__ void cvt4(float4 a, uint2* hi, uint2* lo,
                                     float* ssq) {
  float xs[4] = {a.x, a.y, a.z, a.w};
  union { uint2 q; unsigned short u[4]; } H, L;
#pragma unroll
  for (int e = 0; e < 4; ++e) {
    float x = xs[e];
    unsigned short h = bf16rtne(x);
    float hf = __uint_as_float(((unsigned)h) << 16);
    H.u[e] = h;
    L.u[e] = bf16rtne(x - hf);
    *ssq = fmaf(x, x, *ssq);
  }
  *hi = H.q;
  *lo = L.q;
}

// ---------------- reductions ----------------

__device__ __forceinline__ float waveReduceSum(float v) {
#pragma unroll
  for (int o = 32; o > 0; o >>= 1) v += __shfl_xor(v, o, 64);
  return v;
}

__device__ __forceinline__ float blockReduceSum(float v, float* sbuf) {
  v = waveReduceSum(v);
  int w = threadIdx.x >> 6;
  if ((threadIdx.x & 63) == 0) sbuf[w] = v;
  __syncthreads();
  float r = sbuf[0] + sbuf[1] + sbuf[2] + sbuf[3];
  __syncthreads();
  return r;
}

// ---------------- prep: split [R][1024] f32 into bf16 hi/lo frag layout ----

__global__ __launch_bounds__(256) void prep_bf16_kernel(
    const float* __restrict__ src, float* __restrict__ dst, int R16) {
  int g = blockIdx.x * 256 + threadIdx.x;
  int l = g & 63;
  int mt = (g >> 6) % R16;
  int kb = (g >> 6) / R16;
  int row = mt * 16 + (l & 15);
  int k0 = kb * 32 + ((l >> 4) << 3);
  const float* s = src + (size_t)row * D + k0;
  float4 v0 = *(const float4*)s;
  float4 v1 = *(const float4*)(s + 4);
  float xs[8] = {v0.x, v0.y, v0.z, v0.w, v1.x, v1.y, v1.z, v1.w};
  union { uint4 q; unsigned short u[8]; } H, L;
#pragma unroll
  for (int e = 0; e < 8; ++e) {
    float x = xs[e];
    unsigned short h = bf16rtne(x);
    float hf = __uint_as_float(((unsigned)h) << 16);
    H.u[e] = h;
    L.u[e] = bf16rtne(x - hf);
  }
  char* db = (char*)dst + (size_t)kb * (R16 * 2048) + mt * 2048 + l * 16;
  *(uint4*)db = H.q;
  *(uint4*)(db + 1024) = L.q;
}

// ---------------- MFMA projection GEMM (K-chunked, bf16 single-acc) --------

__global__ __launch_bounds__(256) void mfma_gemm_kernel(
    const float* __restrict__ Afr, const float* __restrict__ Wfr,
    float* __restrict__ part) {
  int t = threadIdx.x;
  int w = t >> 6, l = t & 63;
  int ct = blockIdx.x & 63;
  int kc = blockIdx.x >> 6;
  f32x4 acc[4];
  f32x4 zz = {0.f, 0.f, 0.f, 0.f};
#pragma unroll
  for (int mi = 0; mi < 4; ++mi) acc[mi] = zz;
  const char* ab0 = (const char*)Afr + w * 8192 + l * 16;
  const char* bb0 = (const char*)Wfr + ct * 2048 + l * 16;
#pragma unroll 2
  for (int s = 0; s < 8; ++s) {
    int kb = kc * 8 + s;
    const char* bb = bb0 + (size_t)kb * 131072;
    s16x8 bh = *(const s16x8*)(bb);
    s16x8 bl = *(const s16x8*)(bb + 1024);
    const char* ab = ab0 + (size_t)kb * 32768;
#pragma unroll
    for (int mi = 0; mi < 4; ++mi) {
      s16x8 ah = *(const s16x8*)(ab + mi * 2048);
      s16x8 al = *(const s16x8*)(ab + mi * 2048 + 1024);
      mfma16(acc[mi], ah, bh);
      mfma16(acc[mi], ah, bl);
      mfma16(acc[mi], al, bh);
    }
  }
  float* pb = part + (size_t)kc * 262144 + ct * 16 + (l & 15);
#pragma unroll
  for (int mi = 0; mi < 4; ++mi)
#pragma unroll
    for (int j = 0; j < 4; ++j) {
      int row = w * 64 + mi * 16 + ((l >> 4) << 2) + j;
      pb[(size_t)row * 1024] = acc[mi][j];
    }
}

// ------- reduce partials + bias + LayerNorm + GELU -> Hf bf16 frags --------

__global__ __launch_bounds__(256) void reduce_ln_gelu_kernel(
    const float* __restrict__ part, const float* __restrict__ bias,
    const float* __restrict__ g, const float* __restrict__ b,
    float* __restrict__ Hf) {
  __shared__ float sbuf[4];
  int row = blockIdx.x, t = threadIdx.x;
  const float* p = part + (size_t)row * 1024 + t * 4;
  float4 x0 = *(const float4*)(p);
  float4 x1 = *(const float4*)(p + 262144);
  float4 x2 = *(const float4*)(p + 524288);
  float4 x3 = *(const float4*)(p + 786432);
  float4 bb = *(const float4*)(bias + t * 4);
  float vx = x0.x + x1.x + x2.x + x3.x + bb.x;
  float vy = x0.y + x1.y + x2.y + x3.y + bb.y;
  float vz = x0.z + x1.z + x2.z + x3.z + bb.z;
  float vw = x0.w + x1.w + x2.w + x3.w + bb.w;
  float s = blockReduceSum(vx + vy + vz + vw, sbuf);
  float mu = s * (1.0f / D);
  float dx = vx - mu, dy = vy - mu, dz = vz - mu, dw = vw - mu;
  float ss = blockReduceSum(dx * dx + dy * dy + dz * dz + dw * dw, sbuf);
  float rstd = rsqrtf(ss * (1.0f / D) + 1e-5f);
  float4 gg = *(const float4*)(g + t * 4);
  float4 be = *(const float4*)(b + t * 4);
  float y[4];
  y[0] = dx * rstd * gg.x + be.x;
  y[1] = dy * rstd * gg.y + be.y;
  y[2] = dz * rstd * gg.z + be.z;
  y[3] = dw * rstd * gg.w + be.w;
  const float c = 0.70710678118654752f;
  union { uint2 q; unsigned short u[4]; } H, L;
#pragma unroll
  for (int e = 0; e < 4; ++e) {
    float ye = 0.5f * y[e] * (1.0f + erff(y[e] * c));
    unsigned short h = bf16rtne(ye);
    float hf = __uint_as_float(((unsigned)h) << 16);
    H.u[e] = h;
    L.u[e] = bf16rtne(ye - hf);
  }
  int kb = t >> 3, oct = (t >> 1) & 3;
  char* db = (char*)Hf + (size_t)kb * 32768 + (row >> 4) * 2048 +
             ((row & 15) + oct * 16) * 16 + (t & 1) * 8;
  *(uint2*)db = H.q;
  *(uint2*)(db + 1024) = L.q;
}

// ------- reduce partials + bias + L2 norm -> out_refined + Af bf16 frags ---

__global__ __launch_bounds__(256) void reduce_l2norm_kernel(
    const float* __restrict__ part, const float* __restrict__ bias,
    float* __restrict__ outRef, float* __restrict__ Af) {
  __shared__ float sbuf[4];
  int row = blockIdx.x, t = threadIdx.x;
  const float* p = part + (size_t)row * 1024 + t * 4;
  float4 x0 = *(const float4*)(p);
  float4 x1 = *(const float4*)(p + 262144);
  float4 x2 = *(const float4*)(p + 524288);
  float4 x3 = *(const float4*)(p + 786432);
  float4 bb = *(const float4*)(bias + t * 4);
  float vx = x0.x + x1.x + x2.x + x3.x + bb.x;
  float vy = x0.y + x1.y + x2.y + x3.y + bb.y;
  float vz = x0.z + x1.z + x2.z + x3.z + bb.z;
  float vw = x0.w + x1.w + x2.w + x3.w + bb.w;
  float ss = blockReduceSum(vx * vx + vy * vy + vz * vz + vw * vw, sbuf);
  float inv = 1.0f / fmaxf(sqrtf(ss), 1e-12f);
  float y[4] = {vx * inv, vy * inv, vz * inv, vw * inv};
  *(float4*)(outRef + (size_t)row * D + t * 4) =
      make_float4(y[0], y[1], y[2], y[3]);
  union { uint2 q; unsigned short u[4]; } H, L;
#pragma unroll
  for (int e = 0; e < 4; ++e) {
    unsigned short h = bf16rtne(y[e]);
    float hf = __uint_as_float(((unsigned)h) << 16);
    H.u[e] = h;
    L.u[e] = bf16rtne(y[e] - hf);
  }
  int kb = t >> 3, oct = (t >> 1) & 3;
  char* db = (char*)Af + (size_t)kb * 32768 + (row >> 4) * 2048 +
             ((row & 15) + oct * 16) * 16 + (t & 1) * 8;
  *(uint2*)db = H.q;
  *(uint2*)(db + 1024) = L.q;
}

__global__ void zero_ctrs_kernel(int* c) { c[threadIdx.x] = 0; }

// ---------------- sims GEMM: 8-wave 256x64 tiles, B-only LDS ---------------
// R12: same safety model as R9/R11 (NO manual vmcnt; plain global loads;
// lgkm-only barrier). 512 threads = 8 waves; wave w owns rows
// [w*32, w*32+32) -> per-wave regs ~halved (acc 32 + Afrag 32 + braw 12)
// so 2 blocks/CU = 16 waves/CU (was reg-capped at 8).
// B staging: thread t <-> (row=t>>3, kq=t&7), ds_write_b64 pair; entry
// index XOR swizzle (row&15)^(koct<<2) applied identically on write and
// read (bijective within each 16-entry group) -> write conflicts spread
// over 4 banks, reads stay conflict-free.

#define SBODY(J, BP, ACh, ACl, ANh, ANl, RC, RN, DOPFB, DOPFA, DOCONV)        \
  do {                                                                         \
    if (DOCONV) {                                                              \
      uint2 bh_, bl_;                                                          \
      cvt4(RC, &bh_, &bl_, &ssq);                                              \
      char* bw_ = smem + (1 - (BP)) * 8192 + bwoff;                            \
      *(uint2*)bw_ = bh_;                                                      \
      *(uint2*)(bw_ + 1024) = bl_;                                             \
    }                                                                          \
    if (DOPFA) {                                                               \
      const char* an_ = afbytes + (size_t)((J) + 1) * 32768 + w2x + l * 16;    \
      _Pragma("unroll") for (int mi = 0; mi < 2; ++mi) {                       \
        ANh[mi] = *(const s16x8*)(an_ + mi * 2048);                            \
        ANl[mi] = *(const s16x8*)(an_ + mi * 2048 + 1024);                     \
      }                                                                        \
    }                                                                          \
    if (DOPFB) {                                                               \
      RN = *(const float4*)(bsrc + ((J) + 3) * 32);                            \
    }                                                                          \
    __builtin_amdgcn_s_setprio(1);                                             \
    _Pragma("unroll") for (int ni = 0; ni < 4; ++ni) {                         \
      const char* bb_ = smem + (BP)*8192 + ni * 2048 + lswz;                   \
      s16x8 bh_ = *(const s16x8*)bb_;                                          \
      s16x8 bl_ = *(const s16x8*)(bb_ + 1024);                                 \
      _Pragma("unroll") for (int mi = 0; mi < 2; ++mi) {                       \
        mfma16(acc[mi][ni], ACh[mi], bh_);                                     \
        mfma16(acc[mi][ni], ACh[mi], bl_);                                     \
        mfma16(acc[mi][ni], ACl[mi], bh_);                                     \
      }                                                                        \
    }                                                                          \
    __builtin_amdgcn_s_setprio(0);                                             \
    asm volatile("s_waitcnt lgkmcnt(0)\n\ts_barrier" ::: "memory");            \
    __builtin_amdgcn_sched_barrier(0);                                         \
  } while (0)

__global__ __launch_bounds__(512) void sims_gemm_kernel(
    const float* __restrict__ Afrag, const float* __restrict__ mem,
    float* __restrict__ invn, int* __restrict__ ctr,
    float* __restrict__ simsbuf, int ntiles, int chunk_n0, int stride_cols) {
  __shared__ __align__(16) char smem[16384];  // bufB[2] only
  __shared__ float sInvF[64];
  __shared__ int s_tile;
  const int t = threadIdx.x;
  const int w = t >> 6, l = t & 63;
  const int w2x = w * 4096;  // (w*2) * 2048 : A row-tile base
  // B staging roles: row t>>3 (0..63), k-quad t&7; koct = kq>>1
  const int brow_loc = t >> 3;
  const int kq = t & 7;
  const int koct = kq >> 1;
  const int bwoff = (brow_loc >> 4) * 2048 +
                    (((brow_loc & 15) ^ (koct << 2)) + koct * 16) * 16 +
                    (kq & 1) * 8;
  // read: lane l wants entry (row=ni*16+(l&15), koct=l>>4), same XOR
  const int lswz = (((l & 15) ^ ((l >> 4) << 2)) + ((l >> 4) << 4)) * 16;
  const char* afbytes = (const char*)Afrag;

  while (true) {
    if (t == 0) s_tile = atomicAdd(ctr, 1);
    __syncthreads();
    const int unit = s_tile;
    __syncthreads();
    if (unit >= ntiles) break;
    const int n0 = chunk_n0 + unit * 64;
    const int brow = min(n0 + brow_loc, NMEM - 1);
    const float* bsrc = mem + (size_t)brow * D + kq * 4;

    f32x4 acc[2][4];
    f32x4 zz = {0.f, 0.f, 0.f, 0.f};
#pragma unroll
    for (int mi = 0; mi < 2; ++mi)
#pragma unroll
      for (int ni = 0; ni < 4; ++ni) acc[mi][ni] = zz;
    float ssq = 0.f;

    // register sets: braw r0..r2 (one float4 each), A-frags s0,s1
    float4 r0, r1, r2;
    s16x8 s0h[2], s0l[2], s1h[2], s1l[2];

    // ---- prologue: braw0..2 + A(0) loads (plain), conv(0)->bufB0, barrier
    r0 = *(const float4*)bsrc;
    r1 = *(const float4*)(bsrc + 32);
    r2 = *(const float4*)(bsrc + 64);
    {
      const char* a0_ = afbytes + w2x + l * 16;
#pragma unroll
      for (int mi = 0; mi < 2; ++mi) {
        s0h[mi] = *(const s16x8*)(a0_ + mi * 2048);
        s0l[mi] = *(const s16x8*)(a0_ + mi * 2048 + 1024);
      }
    }
    {
      uint2 bh0, bl0;
      cvt4(r0, &bh0, &bl0, &ssq);
      *(uint2*)(smem + bwoff) = bh0;
      *(uint2*)(smem + bwoff + 1024) = bl0;
    }
    asm volatile("s_waitcnt lgkmcnt(0)\n\ts_barrier" ::: "memory");
    __builtin_amdgcn_sched_barrier(0);

    // ---- steps 0..23 (mod-6 schedule)
#pragma unroll 1
    for (int jb = 0; jb < 24; jb += 6) {
      SBODY(jb + 0, 0, s0h, s0l, s1h, s1l, r1, r0, 1, 1, 1);
      SBODY(jb + 1, 1, s1h, s1l, s0h, s0l, r2, r1, 1, 1, 1);
      SBODY(jb + 2, 0, s0h, s0l, s1h, s1l, r0, r2, 1, 1, 1);
      SBODY(jb + 3, 1, s1h, s1l, s0h, s0l, r1, r0, 1, 1, 1);
      SBODY(jb + 4, 0, s0h, s0l, s1h, s1l, r2, r1, 1, 1, 1);
      SBODY(jb + 5, 1, s1h, s1l, s0h, s0l, r0, r2, 1, 1, 1);
    }
    // ---- steps 24..29 (last braw prefetch at J=28 -> braw31)
    SBODY(24, 0, s0h, s0l, s1h, s1l, r1, r0, 1, 1, 1);
    SBODY(25, 1, s1h, s1l, s0h, s0l, r2, r1, 1, 1, 1);
    SBODY(26, 0, s0h, s0l, s1h, s1l, r0, r2, 1, 1, 1);
    SBODY(27, 1, s1h, s1l, s0h, s0l, r1, r0, 1, 1, 1);
    SBODY(28, 0, s0h, s0l, s1h, s1l, r2, r1, 1, 1, 1);
    SBODY(29, 1, s1h, s1l, s0h, s0l, r0, r2, 0, 1, 1);
    // ---- step 30: conv braw31 (r1), prefetch A31; step 31: compute only
    SBODY(30, 0, s0h, s0l, s1h, s1l, r1, r0, 0, 1, 1);
    SBODY(31, 1, s1h, s1l, s0h, s0l, r2, r1, 0, 0, 0);

    // ---- epilogue: col norms via shfl over the 8 kq lanes, scaled store
    float s2 = ssq + __shfl_xor(ssq, 1, 64);
    s2 = s2 + __shfl_xor(s2, 2, 64);
    s2 = s2 + __shfl_xor(s2, 4, 64);
    float inv = 1.0f / fmaxf(sqrtf(s2), 1e-12f);
    if (kq == 0) {
      sInvF[brow_loc] = inv;
      int col = n0 + brow_loc;
      if (col < NMEM) invn[col] = inv;
    }
    __syncthreads();
    float siv[4];
#pragma unroll
    for (int ni = 0; ni < 4; ++ni) siv[ni] = sInvF[ni * 16 + (l & 15)];
    float* srow = simsbuf + (size_t)(unit * 64);
#pragma unroll
    for (int mi = 0; mi < 2; ++mi)
#pragma unroll
      for (int jj = 0; jj < 4; ++jj) {
        int row = w * 32 + mi * 16 + ((l >> 4) << 2) + jj;
        float* rp = srow + (size_t)row * stride_cols;
#pragma unroll
        for (int ni = 0; ni < 4; ++ni)
          rp[ni * 16 + (l & 15)] = acc[mi][ni][jj] * siv[ni];
      }
    __syncthreads();  // sInvF reads done before next tile overwrites
  }
}

// -------- per-(row, column-segment) top-16 scan over scaled sims -----------

__global__ __launch_bounds__(512) void topk_chunk_kernel(
    const float* __restrict__ simsbuf, int stride_cols, int chunk_n0,
    int nvalid, int seglen, float* __restrict__ cv, int* __restrict__ ci) {
  __shared__ float wvv[8];
  __shared__ int wii[8];
  __shared__ float sbv;
  __shared__ int sbi;
  int row = blockIdx.x & 255;
  int seg = blockIdx.x >> 8;
  int c0beg = seg * seglen;
  int c0end = c0beg + seglen;
  if (c0end > nvalid) c0end = nvalid;
  int t = threadIdx.x;
  const float* S = simsbuf + (size_t)row * stride_cols;
  float tv[16];
  int ti[16];
#pragma unroll
  for (int s = 0; s < 16; ++s) { tv[s] = -FLT_MAX; ti[s] = 2147483647; }
  float curMin = -FLT_MAX;
  for (int c0 = c0beg + t * 4; c0 < c0end; c0 += 2048) {
    float vv[4] = {-FLT_MAX, -FLT_MAX, -FLT_MAX, -FLT_MAX};
    if (c0 + 4 <= c0end) {
      float4 v = *(const float4*)(S + c0);
      vv[0] = v.x; vv[1] = v.y; vv[2] = v.z; vv[3] = v.w;
    } else {
#pragma unroll
      for (int e = 0; e < 4; ++e)
        if (c0 + e < c0end) vv[e] = S[c0 + e];
    }
#pragma unroll
    for (int e = 0; e < 4; ++e) {
      float v = vv[e];
      if (v > curMin) {
        int n = chunk_n0 + c0 + e;
        int ms = 0;
        float mv = tv[0];
#pragma unroll
        for (int s = 1; s < 16; ++s)
          if (tv[s] < mv) { mv = tv[s]; ms = s; }
#pragma unroll
        for (int s = 0; s < 16; ++s)
          if (s == ms) { tv[s] = v; ti[s] = n; }
        curMin = tv[0];
#pragma unroll
        for (int s = 1; s < 16; ++s) curMin = fminf(curMin, tv[s]);
      }
    }
  }
  float lastV = FLT_MAX;
  int lastI = -1;
  for (int pass = 0; pass < TOPK; ++pass) {
    float bv = -FLT_MAX;
    int bi = 2147483647;
#pragma unroll
    for (int s = 0; s < 16; ++s) {
      float v = tv[s];
      int idx = ti[s];
      bool qual = (v < lastV) || (v == lastV && idx > lastI);
      bool bet = (v > bv) || (v == bv && idx < bi);
      if (qual && bet) { bv = v; bi = idx; }
    }
#pragma unroll
    for (int o = 32; o > 0; o >>= 1) {
      float v2 = __shfl_xor(bv, o, 64);
      int i2 = __shfl_xor(bi, o, 64);
      if (v2 > bv || (v2 == bv && i2 < bi)) { bv = v2; bi = i2; }
    }
    if ((t & 63) == 0) { wvv[t >> 6] = bv; wii[t >> 6] = bi; }
    __syncthreads();
    if (t == 0) {
      float fv = wvv[0];
      int fi = wii[0];
#pragma unroll
      for (int u = 1; u < 8; ++u) {
        if (wvv[u] > fv || (wvv[u] == fv && wii[u] < fi)) {
          fv = wvv[u];
          fi = wii[u];
        }
      }
      sbv = fv;
      sbi = fi;
      cv[seg * 4096 + row * TOPK + pass] = fv;
      ci[seg * 4096 + row * TOPK + pass] = fi;
    }
    __syncthreads();
    lastV = sbv;
    lastI = sbi;
  }
}

// ---------------- final merge across candidate lists -----------------------

__global__ __launch_bounds__(64) void final_merge_kernel(
    const float* __restrict__ cand_v, const int* __restrict__ cand_i,
    int nlists, float* __restrict__ out_vals, float* __restrict__ out_idx) {
  int row = blockIdx.x, l = threadIdx.x;
  int nc = nlists * TOPK;
  float mv[8];
  int mi_[8];
#pragma unroll
  for (int u = 0; u < 8; ++u) {
    int p = l + u * 64;
    if (p < nc) {
      int ch = p >> 4;
      mv[u] = cand_v[ch * 4096 + row * TOPK + (p & 15)];
      mi_[u] = cand_i[ch * 4096 + row * TOPK + (p & 15)];
    } else {
      mv[u] = -FLT_MAX;
      mi_[u] = 2147483647;
    }
  }
  float lastV = FLT_MAX;
  int lastI = -1;
  for (int pass = 0; pass < TOPK; ++pass) {
    float bv = -FLT_MAX;
    int bi = 2147483647;
#pragma unroll
    for (int u = 0; u < 8; ++u) {
      bool qual = (mv[u] < lastV) || (mv[u] == lastV && mi_[u] > lastI);
      bool bet = (mv[u] > bv) || (mv[u] == bv && mi_[u] < bi);
      if (qual && bet) { bv = mv[u]; bi = mi_[u]; }
    }
#pragma unroll
    for (int o = 32; o > 0; o >>= 1) {
      float v2 = __shfl_xor(bv, o, 64);
      int i2 = __shfl_xor(bi, o, 64);
      if (v2 > bv || (v2 == bv && i2 < bi)) { bv = v2; bi = i2; }
    }
    bv = __shfl(bv, 0, 64);
    bi = __shfl(bi, 0, 64);
    if (l == 0) {
      out_vals[row * TOPK + pass] = bv;
      out_idx[row * TOPK + pass] = (float)bi;
    }
    lastV = bv;
    lastI = bi;
  }
}

// ---------------- gather retrieved = mem_n[topk_idx] -----------------------

__global__ __launch_bounds__(256) void gather_kernel(
    const float* __restrict__ out_idx, const float* __restrict__ mem,
    const float* __restrict__ invn, float* __restrict__ out_retr) {
  int p = blockIdx.x;
  int idx = (int)out_idx[p];
  float inv = invn[idx];
  int c = threadIdx.x * 4;
  float4 v = *(const float4*)(mem + (size_t)idx * D + c);
  v.x *= inv; v.y *= inv; v.z *= inv; v.w *= inv;
  *(float4*)(out_retr + (size_t)p * D + c) = v;
}

// ---------------- launch ---------------------------------------------------

extern "C" void kernel_launch(void* const* d_in, const int* in_sizes, int n_in,
                              void* d_out, int out_size, void* d_ws,
                              size_t ws_size, hipStream_t stream) {
  const float* query = (const float*)d_in[0];
  const float* W1 = (const float*)d_in[1];
  const float* b1 = (const float*)d_in[2];
  const float* ln_g = (const float*)d_in[3];
  const float* ln_b = (const float*)d_in[4];
  const float* W2 = (const float*)d_in[5];
  const float* b2 = (const float*)d_in[6];
  const float* mem = (const float*)d_in[7];

  float* out = (float*)d_out;
  float* out_refined = out;                    // 262144
  float* out_vals = out + 262144;              // 4096
  float* out_idx = out + 262144 + 4096;        // 4096
  float* out_retr = out + 262144 + 8192;       // 256*16*1024

  float* wsp = (float*)d_ws;
  float* invn = wsp;                           // 100352
  float* Qf = wsp + 100352;                    // 262144 (query frags, then Hf)
  float* Af = wsp + 362496;                    // 262144
  float* W1f = wsp + 624640;                   // 1048576
  float* W2f = wsp + 1673216;                  // 1048576
  float* part = wsp + 2721792;                 // 1048576
  float* cand_v = wsp + 3770368;               // 131072 (32 lists max)
  int* cand_i = (int*)(wsp + 3901440);         // 131072
  int* ctrs = (int*)(wsp + 4032512);           // 64
  float* sims = wsp + 4032576;

  long ws_floats = (long)(ws_size / 4);
  long avail = ws_floats - 4032640;
  int tpc = (int)(avail / 16384);
  if (tpc > NT_TOT) tpc = NT_TOT;
  if (tpc < 1) tpc = 1;
  int nchunk = (NT_TOT + tpc - 1) / tpc;
  if (nchunk > 32) nchunk = 32;
  tpc = (NT_TOT + nchunk - 1) / nchunk;
  int stride = tpc * 64;
  int nseg = (nchunk <= 8) ? 4 : 1;            // nchunk*nseg <= 32

  zero_ctrs_kernel<<<1, 64, 0, stream>>>(ctrs);
  prep_bf16_kernel<<<128, 256, 0, stream>>>(query, Qf, 16);
  prep_bf16_kernel<<<512, 256, 0, stream>>>(W1, W1f, 64);
  prep_bf16_kernel<<<512, 256, 0, stream>>>(W2, W2f, 64);
  mfma_gemm_kernel<<<256, 256, 0, stream>>>(Qf, W1f, part);
  reduce_ln_gelu_kernel<<<256, 256, 0, stream>>>(part, b1, ln_g, ln_b, Qf);
  mfma_gemm_kernel<<<256, 256, 0, stream>>>(Qf, W2f, part);
  reduce_l2norm_kernel<<<256, 256, 0, stream>>>(part, b2, out_refined, Af);
  for (int c = 0; c < nchunk; ++c) {
    int t0 = c * tpc;
    int nt = NT_TOT - t0;
    if (nt > tpc) nt = tpc;
    if (nt <= 0) break;
    int base = t0 * 64;
    sims_gemm_kernel<<<SIMS_BLOCKS, 512, 0, stream>>>(Af, mem, invn, ctrs + c,
                                                      sims, nt, base, stride);
    int nvalid = NMEM - base;
    if (nvalid > nt * 64) nvalid = nt * 64;
    int seglen = ((nvalid + nseg - 1) / nseg + 3) & ~3;
    topk_chunk_kernel<<<256 * nseg, 512, 0, stream>>>(
        sims, stride, base, nvalid, seglen, cand_v + c * nseg * 4096,
        cand_i + c * nseg * 4096);
  }
  final_merge_kernel<<<256, 64, 0, stream>>>(cand_v, cand_i, nchunk * nseg,
                                             out_vals, out_idx);
  gather_kernel<<<BQ * TOPK, 256, 0, stream>>>(out_idx, mem, invn, out_retr);
}